// Round 8
// baseline (99.317 us; speedup 1.0000x reference)
//
#include <hip/hip_runtime.h>
#include <hip/hip_fp16.h>

#define P_PAD 208

typedef __attribute__((ext_vector_type(8))) short f16x8;
typedef __attribute__((ext_vector_type(8))) _Float16 half8;
typedef __attribute__((ext_vector_type(4))) float f32x4;
typedef __attribute__((ext_vector_type(16))) float f32x16;

__device__ __forceinline__ unsigned short f2h(float x) {
    __half h = __float2half(x);           // RNE f32 -> f16
    unsigned short u;
    __builtin_memcpy(&u, &h, 2);
    return u;
}

// async global->LDS, 16B per lane. LDS dest = wave-uniform base + lane*16.
__device__ __forceinline__ void gll16(const void* g, void* l) {
    __builtin_amdgcn_global_load_lds(
        (const __attribute__((address_space(1))) unsigned*)g,
        (__attribute__((address_space(3))) unsigned*)l, 16, 0, 0);
}

// ---------------- kernel 1: L2-normalize rows, f32 -> f16, pad to 208 rows ----
__global__ __launch_bounds__(256) void norm_kernel(
    const float* __restrict__ feats, const float* __restrict__ nfeats,
    unsigned short* __restrict__ fH, unsigned short* __restrict__ nfH,
    unsigned* __restrict__ scoresU)
{
    if (blockIdx.x == 0) {                 // zero score-max accumulators (replay-safe)
        for (int i = threadIdx.x; i < 2048; i += 256) scoresU[i] = 0u;
    }
    int row  = blockIdx.x * 4 + (threadIdx.x >> 6);   // one wave per padded row
    int lane = threadIdx.x & 63;
    const int ROWS_F = 32 * P_PAD;
    const float* src;
    unsigned short* dst;
    int r;
    if (row < ROWS_F) {
        int a = row / P_PAD; r = row % P_PAD;
        src = feats + ((size_t)a * 196 + r) * 128;
        dst = fH + (size_t)row * 128;
    } else {
        int row2 = row - ROWS_F;
        int b = row2 / P_PAD; r = row2 % P_PAD;
        src = nfeats + ((size_t)b * 196 + r) * 128;
        dst = nfH + (size_t)row2 * 128;
    }
    if (r < 196) {
        float2 v = *(const float2*)(src + lane * 2);
        float ss = v.x * v.x + v.y * v.y;
        #pragma unroll
        for (int m = 1; m < 64; m <<= 1) ss += __shfl_xor(ss, m, 64);
        float rn = rsqrtf(ss);
        ushort2 o; o.x = f2h(v.x * rn); o.y = f2h(v.y * rn);
        *(ushort2*)(dst + lane * 2) = o;
    } else {
        *(unsigned int*)(dst + lane * 2) = 0u;   // zero pad rows
    }
}

// ---------------- kernel 2: LDS panels + 32x32x16 MFMA, 16 waves/block ----
// Stage a 208x128 f16 panel (3328 16B chunks), source-side swizzled:
// LDS slot (row, cc) holds global chunk (row, cc ^ (row&7)).  1024 threads.
__device__ __forceinline__ void stage_panel(const f16x8* __restrict__ g, f16x8* l, int tid) {
    int wave = tid >> 6;
    #pragma unroll
    for (int i = 0; i < 3; ++i) {
        int slot = i * 1024 + tid;
        int row = slot >> 4, cc = slot & 15;
        gll16(g + row * 16 + (cc ^ (row & 7)), l + i * 1024 + wave * 64);
    }
    if (tid < 256) {                       // waves 0-3: tail 256 chunks
        int slot = 3072 + tid;
        int row = slot >> 4, cc = slot & 15;
        gll16(g + row * 16 + (cc ^ (row & 7)), l + 3072 + wave * 64);
    }
}

// NM x NQ 32x32 tiles, K=128 (8 k-steps of 16). QM: mask q-tile 6 pad cols.
template <int NM, int NQ, bool QM>
__device__ __forceinline__ void compute_tiles(
    const f16x8* __restrict__ Al, const f16x8* __restrict__ Bl,
    int r0m, int r0q, int lane, unsigned* __restrict__ smax)
{
    int l31 = lane & 31, h = lane >> 5;
    f32x16 acc[NM][NQ];
    #pragma unroll
    for (int m = 0; m < NM; ++m)
        #pragma unroll
        for (int n = 0; n < NQ; ++n)
            #pragma unroll
            for (int r = 0; r < 16; ++r) acc[m][n][r] = 0.0f;

    #pragma unroll
    for (int kk = 0; kk < 8; ++kk) {
        half8 af[NM], bf[NQ];
        #pragma unroll
        for (int m = 0; m < NM; ++m) {
            int row = r0m + m * 32 + l31;
            af[m] = *(const half8*)(Al + ((row << 4) | ((kk * 2 + h) ^ (row & 7))));
        }
        #pragma unroll
        for (int n = 0; n < NQ; ++n) {
            int row = r0q + n * 32 + l31;
            bf[n] = *(const half8*)(Bl + ((row << 4) | ((kk * 2 + h) ^ (row & 7))));
        }
        #pragma unroll
        for (int m = 0; m < NM; ++m)
            #pragma unroll
            for (int n = 0; n < NQ; ++n)
                acc[m][n] = __builtin_amdgcn_mfma_f32_32x32x16_f16(af[m], bf[n], acc[m][n], 0, 0, 0);
    }

    // fold: max over q (n regs + 32 lane-cols), then LDS atomicMax keyed by p
    #pragma unroll
    for (int m = 0; m < NM; ++m) {
        #pragma unroll
        for (int reg = 0; reg < 16; ++reg) {
            float v = acc[m][0][reg];
            if (QM) v = (l31 < 20) ? v : -3.0f;     // q = 176 + l31 valid iff < 196
            #pragma unroll
            for (int n = 1; n < NQ; ++n) v = fmaxf(v, acc[m][n][reg]);
            v = fmaxf(v, __shfl_xor(v, 1, 64));
            v = fmaxf(v, __shfl_xor(v, 2, 64));
            v = fmaxf(v, __shfl_xor(v, 4, 64));
            v = fmaxf(v, __shfl_xor(v, 8, 64));
            v = fmaxf(v, __shfl_xor(v, 16, 64));
            if (l31 == 0) {
                int p = r0m + m * 32 + (reg & 3) + 8 * (reg >> 2) + 4 * h;  // C/D row map
                atomicMax(&smax[p], __float_as_uint(v + 3.0f));  // sim+3 > 0: uint==float order
            }
        }
    }
}

__global__ __launch_bounds__(1024, 4) void simmax_kernel(
    const unsigned short* __restrict__ fH, const unsigned short* __restrict__ nfH,
    const float* __restrict__ mask, float* __restrict__ sp, unsigned* __restrict__ scoresU)
{
    __shared__ f16x8 lds[3 * 3328];       // A | B0 | B1 = 159744 B
    __shared__ unsigned smax[208];
    f16x8* Al = lds;
    f16x8* B0 = lds + 3328;
    f16x8* B1 = lds + 6656;

    int blk = blockIdx.x;
    int a = blk & 31, bg = blk >> 5;      // 256 blocks = 32 a x 8 b-groups, 1/CU
    int b0 = bg * 8;
    int tid = threadIdx.x, wave = tid >> 6, lane = tid & 63;

    stage_panel((const f16x8*)(fH  + (size_t)a  * P_PAD * 128), Al, tid);
    stage_panel((const f16x8*)(nfH + (size_t)b0 * P_PAD * 128), B0, tid);
    if (tid < 208) smax[tid] = 0u;
    __syncthreads();                      // staging drained, smax zeroed

    // wave -> (mg, qg), hand-balanced so each SIMD carries 12-13 MFMA units
    int mg = (0xE4BF6520u >> (2 * wave)) & 3;
    int qg = (0xFFA45209u >> (2 * wave)) & 3;
    int r0m = (mg < 3) ? mg * 64 : 176;   // m-tile pairs {0,1}{2,3}{4,5}, single {6}@176
    int r0q = (qg < 3) ? qg * 64 : 176;

    for (int bi = 0; bi < 8; ++bi) {
        f16x8* Bcur = (bi & 1) ? B1 : B0;
        f16x8* Bnxt = (bi & 1) ? B0 : B1;
        if (bi < 7)                       // async; lands during this bi's compute
            stage_panel((const f16x8*)(nfH + (size_t)(b0 + bi + 1) * P_PAD * 128), Bnxt, tid);

        if (mg < 3) {
            if (qg < 3) compute_tiles<2, 2, false>(Al, Bcur, r0m, r0q, lane, smax);
            else        compute_tiles<2, 1, true >(Al, Bcur, r0m, r0q, lane, smax);
        } else {
            if (qg < 3) compute_tiles<1, 2, false>(Al, Bcur, r0m, r0q, lane, smax);
            else        compute_tiles<1, 1, true >(Al, Bcur, r0m, r0q, lane, smax);
        }
        __syncthreads();                  // all atomics done; Bnxt staged

        // epilogue: one thread per p
        float d = 0.0f;
        if (tid < 208) {
            float sim = __uint_as_float(smax[tid]) - 3.0f;
            smax[tid] = 0u;               // reset for next bi
            if (tid < 196) {
                d = 0.5f * sqrtf(fmaxf(2.0f - 2.0f * sim, 0.0f)) * mask[a * 196 + tid];
                sp[((size_t)a * 196 + tid) * 64 + (b0 + bi)] = d;   // [a][p][b]
            }
        }
        if (wave < 4) {                   // block max over p -> global scores
            d = fmaxf(d, __shfl_xor(d, 1, 64));
            d = fmaxf(d, __shfl_xor(d, 2, 64));
            d = fmaxf(d, __shfl_xor(d, 4, 64));
            d = fmaxf(d, __shfl_xor(d, 8, 64));
            d = fmaxf(d, __shfl_xor(d, 16, 64));
            d = fmaxf(d, __shfl_xor(d, 32, 64));
            if (lane == 0) atomicMax(&scoresU[a * 64 + b0 + bi], __float_as_uint(d));
        }
        __syncthreads();                  // resets visible before next bi's atomics
    }
}

// ---------------- kernel 3: patch mean over b + scores mean ----
__global__ __launch_bounds__(256) void patchmean_kernel(
    const float* __restrict__ sp, const float* __restrict__ scores,
    float* __restrict__ patch, float* __restrict__ out)
{
    int a = blockIdx.x, tid = threadIdx.x;
    if (tid < 196) {
        const f32x4* v = (const f32x4*)(sp + ((size_t)a * 196 + tid) * 64);
        float s = 0.0f;
        #pragma unroll
        for (int j = 0; j < 16; ++j) { f32x4 x = v[j]; s += x[0] + x[1] + x[2] + x[3]; }
        patch[a * 196 + tid] = s * (1.0f / 64.0f);
    }
    if (tid >= 192 && tid < 256) {         // wave 3: scores mean
        int l = tid - 192;
        float s = scores[a * 64 + l];
        #pragma unroll
        for (int m = 1; m < 64; m <<= 1) s += __shfl_xor(s, m, 64);
        if (l == 0) out[a] = s * (1.0f / 64.0f);
    }
}

// ---------------- kernel 4: bilinear 14x14 -> 224x224, 8-row bands ----
__global__ __launch_bounds__(256) void upsample_kernel(
    const float* __restrict__ patch, float* __restrict__ out)
{
    int bid = blockIdx.x;
    int a = bid / 28, band = bid % 28;
    __shared__ float pt[196];
    if (threadIdx.x < 196) pt[threadIdx.x] = patch[a * 196 + threadIdx.x];
    __syncthreads();

    float* op = out + 32 + (size_t)a * 50176 + band * 8 * 224;
    for (int t = threadIdx.x; t < 8 * 224; t += 256) {
        int h = band * 8 + (t / 224), w = t % 224;
        float sh = fmaxf((h + 0.5f) * 0.0625f - 0.5f, 0.0f);   // 14/224 = 1/16
        float sw = fmaxf((w + 0.5f) * 0.0625f - 0.5f, 0.0f);
        int h0 = (int)sh, w0 = (int)sw;
        int h1 = min(h0 + 1, 13), w1 = min(w0 + 1, 13);
        float fh = sh - (float)h0, fw = sw - (float)w0;
        float v00 = pt[h0 * 14 + w0], v01 = pt[h0 * 14 + w1];
        float v10 = pt[h1 * 14 + w0], v11 = pt[h1 * 14 + w1];
        op[t] = (1.0f - fh) * ((1.0f - fw) * v00 + fw * v01)
              +         fh  * ((1.0f - fw) * v10 + fw * v11);
    }
}

extern "C" void kernel_launch(void* const* d_in, const int* in_sizes, int n_in,
                              void* d_out, int out_size, void* d_ws, size_t ws_size,
                              hipStream_t stream) {
    const float* feats  = (const float*)d_in[0];   // [32,196,128]
    const float* nfeats = (const float*)d_in[1];   // [64,196,128]
    const float* mask   = (const float*)d_in[2];   // [32,196]
    float* out = (float*)d_out;                    // 32 + 32*224*224

    char* w = (char*)d_ws;
    unsigned short* fH  = (unsigned short*)(w);            // 32*208*128 f16 = 1,703,936 B
    unsigned short* nfH = (unsigned short*)(w + 1703936);  // 64*208*128 f16 = 3,407,872 B
    float* sp     = (float*)(w + 5111808);                 // 32*196*64 f32  = 1,605,632 B
    float* scores = (float*)(w + 6717440);                 // 2048 f32
    float* patch  = (float*)(w + 6725632);                 // 32*196 f32

    norm_kernel<<<4992, 256, 0, stream>>>(feats, nfeats, fH, nfH, (unsigned*)scores);
    simmax_kernel<<<256, 1024, 0, stream>>>(fH, nfH, mask, sp, (unsigned*)scores);
    patchmean_kernel<<<32, 256, 0, stream>>>(sp, scores, patch, out);
    upsample_kernel<<<896, 256, 0, stream>>>(patch, out);
}

// Round 10
// 51.551 us; speedup vs baseline: 1.9266x; 1.9266x over previous
//
#include <hip/hip_runtime.h>
#include <hip/hip_fp16.h>

#define P_PAD 208

typedef __attribute__((ext_vector_type(8))) short f16x8;
typedef __attribute__((ext_vector_type(8))) _Float16 half8;
typedef __attribute__((ext_vector_type(4))) float f32x4;
typedef __attribute__((ext_vector_type(16))) float f32x16;

__device__ __forceinline__ unsigned short f2h(float x) {
    __half h = __float2half(x);           // RNE f32 -> f16
    unsigned short u;
    __builtin_memcpy(&u, &h, 2);
    return u;
}

// async global->LDS, 16B per lane. LDS dest = wave-uniform base + lane*16.
__device__ __forceinline__ void gll16(const void* g, void* l) {
    __builtin_amdgcn_global_load_lds(
        (const __attribute__((address_space(1))) unsigned*)g,
        (__attribute__((address_space(3))) unsigned*)l, 16, 0, 0);
}

// ---------------- kernel 1: L2-normalize rows, f32 -> f16, pad to 208 rows ----
__global__ __launch_bounds__(256) void norm_kernel(
    const float* __restrict__ feats, const float* __restrict__ nfeats,
    unsigned short* __restrict__ fH, unsigned short* __restrict__ nfH,
    unsigned* __restrict__ scoresU)
{
    if (blockIdx.x == 0) {                 // zero score-max accumulators (replay-safe)
        for (int i = threadIdx.x; i < 2048; i += 256) scoresU[i] = 0u;
    }
    int row  = blockIdx.x * 4 + (threadIdx.x >> 6);   // one wave per padded row
    int lane = threadIdx.x & 63;
    const int ROWS_F = 32 * P_PAD;
    const float* src;
    unsigned short* dst;
    int r;
    if (row < ROWS_F) {
        int a = row / P_PAD; r = row % P_PAD;
        src = feats + ((size_t)a * 196 + r) * 128;
        dst = fH + (size_t)row * 128;
    } else {
        int row2 = row - ROWS_F;
        int b = row2 / P_PAD; r = row2 % P_PAD;
        src = nfeats + ((size_t)b * 196 + r) * 128;
        dst = nfH + (size_t)row2 * 128;
    }
    if (r < 196) {
        float2 v = *(const float2*)(src + lane * 2);
        float ss = v.x * v.x + v.y * v.y;
        #pragma unroll
        for (int m = 1; m < 64; m <<= 1) ss += __shfl_xor(ss, m, 64);
        float rn = rsqrtf(ss);
        ushort2 o; o.x = f2h(v.x * rn); o.y = f2h(v.y * rn);
        *(ushort2*)(dst + lane * 2) = o;
    } else {
        *(unsigned int*)(dst + lane * 2) = 0u;   // zero pad rows
    }
}

// ---------------- kernel 2: swapped-operand MFMA, lane-local q-max ----
// Stage a 208x128 f16 panel (3328 16B chunks), source-side swizzled:
// LDS slot (row, cc) holds global chunk (row, cc ^ (row&7)).  1024 threads.
__device__ __forceinline__ void stage_panel(const f16x8* __restrict__ g, f16x8* l, int tid) {
    int wave = tid >> 6;
    #pragma unroll
    for (int i = 0; i < 3; ++i) {
        int slot = i * 1024 + tid;
        int row = slot >> 4, cc = slot & 15;
        gll16(g + row * 16 + (cc ^ (row & 7)), l + i * 1024 + wave * 64);
    }
    if (tid < 256) {                       // waves 0-3: tail 256 chunks
        int slot = 3072 + tid;
        int row = slot >> 4, cc = slot & 15;
        gll16(g + row * 16 + (cc ^ (row & 7)), l + 3072 + wave * 64);
    }
}

// NQ q-tiles (A-operand = nf) x NP p-tiles (B-operand = f), K=128.
// C/D: col = lane&31 = p, row = q = (reg&3)+8*(reg>>2)+4*(lane>>5).
// Max over q = in-register fmax; one shfl_xor(32) + LDS atomicMax per p-tile.
// QM: q-tile at 176, rows valid iff rowidx < 20 (q = 176+rowidx < 196).
template <int NQ, int NP, bool QM>
__device__ __forceinline__ void cells(
    const f16x8* __restrict__ Np, const f16x8* __restrict__ Fp,
    int q0, int p0, int lane, unsigned* __restrict__ smax)
{
    int l31 = lane & 31, h = lane >> 5;
    f32x16 acc[NQ][NP];
    #pragma unroll
    for (int m = 0; m < NQ; ++m)
        #pragma unroll
        for (int n = 0; n < NP; ++n)
            #pragma unroll
            for (int r = 0; r < 16; ++r) acc[m][n][r] = 0.0f;

    #pragma unroll
    for (int kk = 0; kk < 8; ++kk) {
        half8 qa[NQ], pb[NP];
        #pragma unroll
        for (int m = 0; m < NQ; ++m) {
            int row = q0 + m * 32 + l31;
            qa[m] = *(const half8*)(Np + ((row << 4) | ((kk * 2 + h) ^ (row & 7))));
        }
        #pragma unroll
        for (int n = 0; n < NP; ++n) {
            int row = p0 + n * 32 + l31;
            pb[n] = *(const half8*)(Fp + ((row << 4) | ((kk * 2 + h) ^ (row & 7))));
        }
        #pragma unroll
        for (int m = 0; m < NQ; ++m)
            #pragma unroll
            for (int n = 0; n < NP; ++n)
                acc[m][n] = __builtin_amdgcn_mfma_f32_32x32x16_f16(qa[m], pb[n], acc[m][n], 0, 0, 0);
    }

    // fold max over q: all in-register (4 parallel chains for ILP), then 1 shfl
    #pragma unroll
    for (int n = 0; n < NP; ++n) {
        float c0 = -3.0f, c1 = -3.0f, c2 = -3.0f, c3 = -3.0f;
        #pragma unroll
        for (int m = 0; m < NQ; ++m) {
            #pragma unroll
            for (int reg = 0; reg < 16; ++reg) {
                float x = acc[m][n][reg];
                if (QM) {
                    int rowidx = (reg & 3) + 8 * (reg >> 2) + 4 * h;
                    x = (rowidx < 20) ? x : -3.0f;
                }
                if ((reg & 3) == 0) c0 = fmaxf(c0, x);
                else if ((reg & 3) == 1) c1 = fmaxf(c1, x);
                else if ((reg & 3) == 2) c2 = fmaxf(c2, x);
                else c3 = fmaxf(c3, x);
            }
        }
        float v = fmaxf(fmaxf(c0, c1), fmaxf(c2, c3));
        v = fmaxf(v, __shfl_xor(v, 32, 64));            // combine row-halves (h)
        if (h == 0)                                      // lanes 0-31: one per p
            atomicMax(&smax[p0 + n * 32 + l31],          // FIX: include n*32
                      __float_as_uint(v + 3.0f));        // sim+3 > 0: uint==float order
    }
}

__global__ __launch_bounds__(1024, 4) void simmax_kernel(
    const unsigned short* __restrict__ fH, const unsigned short* __restrict__ nfH,
    const float* __restrict__ mask, float* __restrict__ sp, unsigned* __restrict__ scoresU)
{
    __shared__ f16x8 lds[3 * 3328];       // F | B0 | B1 = 159744 B
    __shared__ unsigned smax[208];
    f16x8* Fl = lds;
    f16x8* B0 = lds + 3328;
    f16x8* B1 = lds + 6656;

    int blk = blockIdx.x;
    int a = blk & 31, bg = blk >> 5;      // 256 blocks = 32 a x 8 b-groups, 1/CU
    int b0 = bg * 8;
    int tid = threadIdx.x, wave = tid >> 6, lane = tid & 63;

    stage_panel((const f16x8*)(fH  + (size_t)a  * P_PAD * 128), Fl, tid);
    stage_panel((const f16x8*)(nfH + (size_t)b0 * P_PAD * 128), B0, tid);
    if (tid < 208) smax[tid] = 0u;
    __syncthreads();                      // staging drained, smax zeroed

    for (int bi = 0; bi < 8; ++bi) {
        f16x8* Bcur = (bi & 1) ? B1 : B0;
        f16x8* Bnxt = (bi & 1) ? B0 : B1;
        if (bi < 7)                       // async; lands during this bi's compute
            stage_panel((const f16x8*)(nfH + (size_t)(b0 + bi + 1) * P_PAD * 128), Bnxt, tid);

        // 49 MFMA-units over 16 waves; SIMD w&3 loads: 12,12,12,13 units
        switch (wave) {
            case 0:  cells<2,2,false>(Bcur, Fl,   0,   0, lane, smax); break;
            case 4:  cells<2,2,false>(Bcur, Fl,  64,  64, lane, smax); break;
            case 8:  cells<1,2,true >(Bcur, Fl, 176,   0, lane, smax); break;
            case 12: cells<1,2,true >(Bcur, Fl, 176,  64, lane, smax); break;
            case 1:  cells<2,2,false>(Bcur, Fl,   0,  64, lane, smax); break;
            case 5:  cells<2,2,false>(Bcur, Fl,  64, 128, lane, smax); break;
            case 9:  cells<1,2,true >(Bcur, Fl, 176, 128, lane, smax); break;
            case 13: cells<2,1,false>(Bcur, Fl,   0, 176, lane, smax); break;
            case 2:  cells<2,2,false>(Bcur, Fl,   0, 128, lane, smax); break;
            case 6:  cells<2,2,false>(Bcur, Fl, 128,   0, lane, smax); break;
            case 10: cells<2,1,false>(Bcur, Fl,  64, 176, lane, smax); break;
            case 14: cells<2,1,false>(Bcur, Fl, 128, 176, lane, smax); break;
            case 3:  cells<2,2,false>(Bcur, Fl,  64,   0, lane, smax); break;
            case 7:  cells<2,2,false>(Bcur, Fl, 128,  64, lane, smax); break;
            case 11: cells<2,2,false>(Bcur, Fl, 128, 128, lane, smax); break;
            default: cells<1,1,true >(Bcur, Fl, 176, 176, lane, smax); break;
        }
        __syncthreads();                  // all atomics done; Bnxt staged

        // epilogue: one thread per p
        float d = 0.0f;
        if (tid < 208) {
            float sim = __uint_as_float(smax[tid]) - 3.0f;
            smax[tid] = 0u;               // reset for next bi
            if (tid < 196) {
                d = 0.5f * sqrtf(fmaxf(2.0f - 2.0f * sim, 0.0f)) * mask[a * 196 + tid];
                sp[((size_t)a * 196 + tid) * 64 + (b0 + bi)] = d;   // [a][p][b]
            }
        }
        if (wave < 4) {                   // block max over p -> global scores
            d = fmaxf(d, __shfl_xor(d, 1, 64));
            d = fmaxf(d, __shfl_xor(d, 2, 64));
            d = fmaxf(d, __shfl_xor(d, 4, 64));
            d = fmaxf(d, __shfl_xor(d, 8, 64));
            d = fmaxf(d, __shfl_xor(d, 16, 64));
            d = fmaxf(d, __shfl_xor(d, 32, 64));
            if (lane == 0) atomicMax(&scoresU[a * 64 + b0 + bi], __float_as_uint(d));
        }
        __syncthreads();                  // resets visible before next bi's atomics
    }
}

// ---------------- kernel 3: patch mean over b + scores mean ----
__global__ __launch_bounds__(256) void patchmean_kernel(
    const float* __restrict__ sp, const float* __restrict__ scores,
    float* __restrict__ patch, float* __restrict__ out)
{
    int a = blockIdx.x, tid = threadIdx.x;
    if (tid < 196) {
        const f32x4* v = (const f32x4*)(sp + ((size_t)a * 196 + tid) * 64);
        float s = 0.0f;
        #pragma unroll
        for (int j = 0; j < 16; ++j) { f32x4 x = v[j]; s += x[0] + x[1] + x[2] + x[3]; }
        patch[a * 196 + tid] = s * (1.0f / 64.0f);
    }
    if (tid >= 192 && tid < 256) {         // wave 3: scores mean
        int l = tid - 192;
        float s = scores[a * 64 + l];
        #pragma unroll
        for (int m = 1; m < 64; m <<= 1) s += __shfl_xor(s, m, 64);
        if (l == 0) out[a] = s * (1.0f / 64.0f);
    }
}

// ---------------- kernel 4: bilinear 14x14 -> 224x224, 8-row bands ----
__global__ __launch_bounds__(256) void upsample_kernel(
    const float* __restrict__ patch, float* __restrict__ out)
{
    int bid = blockIdx.x;
    int a = bid / 28, band = bid % 28;
    __shared__ float pt[196];
    if (threadIdx.x < 196) pt[threadIdx.x] = patch[a * 196 + threadIdx.x];
    __syncthreads();

    float* op = out + 32 + (size_t)a * 50176 + band * 8 * 224;
    for (int t = threadIdx.x; t < 8 * 224; t += 256) {
        int h = band * 8 + (t / 224), w = t % 224;
        float sh = fmaxf((h + 0.5f) * 0.0625f - 0.5f, 0.0f);   // 14/224 = 1/16
        float sw = fmaxf((w + 0.5f) * 0.0625f - 0.5f, 0.0f);
        int h0 = (int)sh, w0 = (int)sw;
        int h1 = min(h0 + 1, 13), w1 = min(w0 + 1, 13);
        float fh = sh - (float)h0, fw = sw - (float)w0;
        float v00 = pt[h0 * 14 + w0], v01 = pt[h0 * 14 + w1];
        float v10 = pt[h1 * 14 + w0], v11 = pt[h1 * 14 + w1];
        op[t] = (1.0f - fh) * ((1.0f - fw) * v00 + fw * v01)
              +         fh  * ((1.0f - fw) * v10 + fw * v11);
    }
}

extern "C" void kernel_launch(void* const* d_in, const int* in_sizes, int n_in,
                              void* d_out, int out_size, void* d_ws, size_t ws_size,
                              hipStream_t stream) {
    const float* feats  = (const float*)d_in[0];   // [32,196,128]
    const float* nfeats = (const float*)d_in[1];   // [64,196,128]
    const float* mask   = (const float*)d_in[2];   // [32,196]
    float* out = (float*)d_out;                    // 32 + 32*224*224

    char* w = (char*)d_ws;
    unsigned short* fH  = (unsigned short*)(w);            // 32*208*128 f16 = 1,703,936 B
    unsigned short* nfH = (unsigned short*)(w + 1703936);  // 64*208*128 f16 = 3,407,872 B
    float* sp     = (float*)(w + 5111808);                 // 32*196*64 f32  = 1,605,632 B
    float* scores = (float*)(w + 6717440);                 // 2048 f32
    float* patch  = (float*)(w + 6725632);                 // 32*196 f32

    norm_kernel<<<4992, 256, 0, stream>>>(feats, nfeats, fH, nfH, (unsigned*)scores);
    simmax_kernel<<<256, 1024, 0, stream>>>(fH, nfH, mask, sp, (unsigned*)scores);
    patchmean_kernel<<<32, 256, 0, stream>>>(sp, scores, patch, out);
    upsample_kernel<<<896, 256, 0, stream>>>(patch, out);
}